// Round 2
// baseline (943.317 us; speedup 1.0000x reference)
//
// MOE anomaly detection — MI355X round 2.
// Fix vs r1: k_tail final butterfly already sums each expert exactly once
// (XOR-span{4,8,16,32} touches one lane per expert group); removed the
// spurious *0.25f. No other changes — this round is for correctness + profile.
#include <hip/hip_runtime.h>
#include <stdint.h>

#define NTOK 65536
#define DDIM 512
#define NE   16
#define NH1  128
#define NH2  64
#define NR   32

typedef __attribute__((ext_vector_type(8))) short short8;
typedef __attribute__((ext_vector_type(4))) unsigned short ushort4_t;
typedef __attribute__((ext_vector_type(4))) float f32x4;

__device__ __forceinline__ unsigned short f2bf(float f) {
  union { float f; uint32_t u; } v; v.f = f;
  uint32_t u = v.u;
  return (unsigned short)((u + 0x7FFFu + ((u >> 16) & 1u)) >> 16);
}
__device__ __forceinline__ float bf2f(unsigned short h) {
  union { uint32_t u; float f; } v; v.u = ((uint32_t)h) << 16;
  return v.f;
}

// ---------------- ws layout (bytes) ----------------
#define OFF_XT     ((size_t)0)            // bf16 x^T [512][65536]      67108864
#define OFF_H2     ((size_t)67108864)     // bf16 h2_pre [N][16][64]   134217728
#define OFF_COVP   ((size_t)201326592)    // f32 cov partials [32][512][512] 33554432
#define OFF_C      ((size_t)234881024)    // f32 C [512][512]            1048576
#define OFF_GATE   ((size_t)235929600)    // f32 gate [N][16]            4194304
#define OFF_W1T    ((size_t)240123904)    // bf16 W1t [16][128][512]     2097152
#define OFF_W2T    ((size_t)242221056)    // bf16 W2t [16][64][128]       262144
#define OFF_WGT    ((size_t)242483200)    // bf16 Wgt [16][512]            16384
#define OFF_V      ((size_t)242499584)    // f32 v=W3@Ws [16][64]           4096
#define OFF_XBAR   ((size_t)242503680)    // f32 xbar[512]  (zero region start)
#define OFF_BN2S   ((size_t)242505728)    // f32 bn2 sum[1024]
#define OFF_BN2SS  ((size_t)242509824)    // f32 bn2 sumsq[1024]
#define OFF_MEAN1  ((size_t)242513920)    // f32 mean1[16][128]
#define OFF_ISTD1  ((size_t)242522112)    // f32 istd1[16][128]
// total 242530304 B (~232 MB)

// ============ k_wprep: weight convert/transpose + fold + zero accumulators ============
__global__ __launch_bounds__(256) void k_wprep(
    const float* __restrict__ W1, const float* __restrict__ W2,
    const float* __restrict__ W3, const float* __restrict__ Wg,
    const float* __restrict__ Ws,
    unsigned short* __restrict__ W1t, unsigned short* __restrict__ W2t,
    unsigned short* __restrict__ Wgt, float* __restrict__ vfold,
    float* __restrict__ zeroreg)
{
  int b = blockIdx.x, t = threadIdx.x;
  if (b < 512) {            // W1 [E][D][H1] -> W1t [E][H1][D]
    int f = b * 256 + t;
    int h = f & 127, d8 = (f >> 7) & 63, e = f >> 13;
    short8 s;
#pragma unroll
    for (int i = 0; i < 8; ++i)
      s[i] = (short)f2bf(W1[((e * DDIM + d8 * 8 + i) * NH1) + h]);
    *(short8*)&W1t[(e * NH1 + h) * DDIM + d8 * 8] = s;
  } else if (b < 576) {     // W2 [E][H1][H2] -> W2t [E][H2][H1]
    int f = (b - 512) * 256 + t;
    int k2 = f & 63, h8 = (f >> 6) & 15, e = f >> 10;
    short8 s;
#pragma unroll
    for (int i = 0; i < 8; ++i)
      s[i] = (short)f2bf(W2[((e * NH1 + h8 * 8 + i) * NH2) + k2]);
    *(short8*)&W2t[(e * NH2 + k2) * NH1 + h8 * 8] = s;
  } else if (b < 580) {     // Wg [D][E] -> Wgt [E][D]
    int f = (b - 576) * 256 + t;
    if (f < NE * (DDIM / 8)) {
      int e = f & 15, d8 = f >> 4;
      short8 s;
#pragma unroll
      for (int i = 0; i < 8; ++i)
        s[i] = (short)f2bf(Wg[(d8 * 8 + i) * NE + e]);
      *(short8*)&Wgt[e * DDIM + d8 * 8] = s;
    }
  } else if (b < 584) {     // vfold[e][h] = sum_r W3[e][h][r]*Ws[r]
    int f = (b - 580) * 256 + t;
    if (f < NE * NH2) {
      int h = f & 63, e = f >> 6;
      float a = 0.f;
#pragma unroll
      for (int r = 0; r < NR; ++r) a += W3[(e * NH2 + h) * NR + r] * Ws[r];
      vfold[e * NH2 + h] = a;
    }
  } else {                  // zero xbar(512)+bn2s(1024)+bn2ss(1024)
    int f = (b - 584) * 256 + t;
    if (f < 2560) zeroreg[f] = 0.f;
  }
}

// ============ k_prep: x fp32 -> bf16 transposed x^T, plus column sums ============
__global__ __launch_bounds__(256) void k_prep(const float* __restrict__ x,
                                              unsigned short* __restrict__ xT,
                                              float* __restrict__ xbar)
{
  __shared__ unsigned short tl[64 * 72];   // [d][n] transposed tile, pad 72
  __shared__ float red[16 * 64];
  int b = blockIdx.x, t = threadIdx.x;
  int dt = b >> 10, nt = b & 1023;
  int d0 = dt * 64, n0 = nt * 64;
  int rg = t >> 4, c4 = (t & 15) * 4;
  float s0 = 0, s1 = 0, s2 = 0, s3 = 0;
#pragma unroll
  for (int i = 0; i < 4; ++i) {
    int r = i * 16 + rg;
    float4 v = *(const float4*)&x[(size_t)(n0 + r) * DDIM + d0 + c4];
    s0 += v.x; s1 += v.y; s2 += v.z; s3 += v.w;
    tl[(c4 + 0) * 72 + r] = f2bf(v.x);
    tl[(c4 + 1) * 72 + r] = f2bf(v.y);
    tl[(c4 + 2) * 72 + r] = f2bf(v.z);
    tl[(c4 + 3) * 72 + r] = f2bf(v.w);
  }
  red[rg * 64 + c4 + 0] = s0;
  red[rg * 64 + c4 + 1] = s1;
  red[rg * 64 + c4 + 2] = s2;
  red[rg * 64 + c4 + 3] = s3;
  __syncthreads();
  if (t < 64) {
    float s = 0;
#pragma unroll
    for (int k = 0; k < 16; ++k) s += red[k * 64 + t];
    atomicAdd(&xbar[d0 + t], s);
  }
#pragma unroll
  for (int i = 0; i < 2; ++i) {
    int d = i * 32 + (t >> 3), n8 = t & 7;
    short8 v = *(short8*)&tl[d * 72 + n8 * 8];
    *(short8*)&xT[(size_t)(d0 + d) * NTOK + n0 + n8 * 8] = v;
  }
}

// ============ k_cov: C partials = x^T x, MFMA fed straight from global x^T ============
__global__ __launch_bounds__(512) void k_cov(const unsigned short* __restrict__ xT,
                                             float* __restrict__ covp)
{
  int b = blockIdx.x, t = threadIdx.x;
  int tile = b & 15, chunk = b >> 4;       // 16 tiles x 32 chunks
  int i0 = (tile >> 2) * 128, j0 = (tile & 3) * 128;
  int n0 = chunk * 2048;
  int l = t & 63, wid = t >> 6;            // 8 waves: 2x4
  int rb = i0 + (wid >> 2) * 64;
  int cb = j0 + (wid & 3) * 32;
  int lr = l & 15, lk = (l >> 4) * 8;
  f32x4 acc[4][2];
#pragma unroll
  for (int m = 0; m < 4; ++m)
#pragma unroll
    for (int n = 0; n < 2; ++n) acc[m][n] = (f32x4){0.f, 0.f, 0.f, 0.f};
  for (int it = 0; it < 64; ++it) {
    int k = n0 + it * 32 + lk;
    short8 av[4], bv[2];
#pragma unroll
    for (int m = 0; m < 4; ++m)
      av[m] = *(const short8*)&xT[(size_t)(rb + m * 16 + lr) * NTOK + k];
#pragma unroll
    for (int n = 0; n < 2; ++n)
      bv[n] = *(const short8*)&xT[(size_t)(cb + n * 16 + lr) * NTOK + k];
#pragma unroll
    for (int m = 0; m < 4; ++m)
#pragma unroll
      for (int n = 0; n < 2; ++n)
        acc[m][n] = __builtin_amdgcn_mfma_f32_16x16x32_bf16(av[m], bv[n], acc[m][n], 0, 0, 0);
  }
  int orow = (l >> 4) * 4;
#pragma unroll
  for (int m = 0; m < 4; ++m)
#pragma unroll
    for (int n = 0; n < 2; ++n)
#pragma unroll
      for (int r = 0; r < 4; ++r) {
        int gr = rb + m * 16 + orow + r;
        int gc = cb + n * 16 + lr;
        covp[(size_t)chunk * 262144 + gr * 512 + gc] = acc[m][n][r];
      }
}

__global__ __launch_bounds__(256) void k_covred(const float* __restrict__ covp,
                                                float* __restrict__ C)
{
  int idx = blockIdx.x * 256 + threadIdx.x;
  float s = 0.f;
#pragma unroll 4
  for (int c = 0; c < 32; ++c) s += covp[(size_t)c * 262144 + idx];
  C[idx] = s;
}

// ============ k_bn1: mean1 = w.xbar/N ; var1 = w^T C w /N - mean1^2 ============
__global__ __launch_bounds__(256) void k_bn1(const float* __restrict__ C,
                                             const float* __restrict__ xbar,
                                             const unsigned short* __restrict__ W1t,
                                             float* __restrict__ mean1,
                                             float* __restrict__ istd1)
{
  __shared__ float wl[8][512];
  __shared__ float rq[256][8];
  __shared__ float rm[256][8];
  int b = blockIdx.x, t = threadIdx.x;
  int e = b >> 4, ho = (b & 15) * 8;
  for (int f = t; f < 8 * 512; f += 256) {
    int c = f >> 9, d = f & 511;
    wl[c][d] = bf2f(W1t[(e * NH1 + ho + c) * DDIM + d]);
  }
  __syncthreads();
  float q[8] = {0, 0, 0, 0, 0, 0, 0, 0};
  float m[8] = {0, 0, 0, 0, 0, 0, 0, 0};
#pragma unroll
  for (int half = 0; half < 2; ++half) {
    int i = half * 256 + t;
    float rd[8] = {0, 0, 0, 0, 0, 0, 0, 0};
    const float* crow = &C[i * 512];
    for (int j = 0; j < 512; j += 4) {
      float4 cv = *(const float4*)&crow[j];
#pragma unroll
      for (int c = 0; c < 8; ++c)
        rd[c] += cv.x * wl[c][j] + cv.y * wl[c][j + 1] + cv.z * wl[c][j + 2] + cv.w * wl[c][j + 3];
    }
    float xb = xbar[i];
#pragma unroll
    for (int c = 0; c < 8; ++c) { q[c] += wl[c][i] * rd[c]; m[c] += wl[c][i] * xb; }
  }
#pragma unroll
  for (int c = 0; c < 8; ++c) { rq[t][c] = q[c]; rm[t][c] = m[c]; }
  __syncthreads();
  for (int s = 128; s > 0; s >>= 1) {
    if (t < s)
#pragma unroll
      for (int c = 0; c < 8; ++c) { rq[t][c] += rq[t + s][c]; rm[t][c] += rm[t + s][c]; }
    __syncthreads();
  }
  if (t < 8) {
    float mean = rm[0][t] * (1.f / 65536.f);
    float var = rq[0][t] * (1.f / 65536.f) - mean * mean;
    mean1[e * NH1 + ho + t] = mean;
    istd1[e * NH1 + ho + t] = rsqrtf(var + 1e-4f);
  }
}

// ============ k_main: gating + per-expert GEMM1->BN1->lrelu->GEMM2 -> h2_pre ============
__global__ __launch_bounds__(256) void k_main(
    const float* __restrict__ x, const unsigned short* __restrict__ Wgt,
    const unsigned short* __restrict__ W1t, const unsigned short* __restrict__ W2t,
    const float* __restrict__ bg, const float* __restrict__ ln_g,
    const float* __restrict__ ln_b, const float* __restrict__ mean1,
    const float* __restrict__ istd1, float* __restrict__ gate,
    unsigned short* __restrict__ h2p)
{
  __shared__ unsigned short xl[64 * 512];   // 64KB, XOR-swizzled rows
  __shared__ unsigned short h1l[64 * 128];  // 16KB, XOR-swizzled
  int t = threadIdx.x;
  int n0 = blockIdx.x * 64;
  int l = t & 63, wid = t >> 6;
  int lr = l & 15, lg = l >> 4;

  {  // stage x -> bf16 LDS (swizzle: short-idx ^= (row&7)<<3  == byte ^ (row&7)<<4)
    int rhalf = t >> 7;
    int c4 = (t & 127) * 4;
    for (int i = 0; i < 32; ++i) {
      int r = i * 2 + rhalf;
      float4 v = *(const float4*)&x[(size_t)(n0 + r) * DDIM + c4];
      ushort4_t u;
      u.x = f2bf(v.x); u.y = f2bf(v.y); u.z = f2bf(v.z); u.w = f2bf(v.w);
      int idx = (r * DDIM + c4) ^ ((r & 7) << 3);
      *(ushort4_t*)&xl[idx] = u;
    }
  }
  __syncthreads();

  {  // gating: g = x@Wg + bg -> LN -> softmax -> gate
    int rb = wid * 16;
    f32x4 ga = (f32x4){0.f, 0.f, 0.f, 0.f};
    for (int ks = 0; ks < 16; ++ks) {
      int k = ks * 32 + lg * 8;
      int ar = rb + lr;
      short8 av = *(short8*)&xl[(ar * DDIM + k) ^ ((ar & 7) << 3)];
      short8 bv = *(const short8*)&Wgt[lr * DDIM + k];
      ga = __builtin_amdgcn_mfma_f32_16x16x32_bf16(av, bv, ga, 0, 0, 0);
    }
    float gamma = ln_g[lr], beta = ln_b[lr], bgv = bg[lr];
#pragma unroll
    for (int r = 0; r < 4; ++r) {
      int row = rb + lg * 4 + r;
      float g = ga[r] + bgv;
      float s1 = g, s2 = g * g;
#pragma unroll
      for (int mk = 1; mk <= 8; mk <<= 1) { s1 += __shfl_xor(s1, mk); s2 += __shfl_xor(s2, mk); }
      float mu = s1 * (1.f / 16.f);
      float var = s2 * (1.f / 16.f) - mu * mu;
      float gn = (g - mu) * rsqrtf(var + 1e-5f) * gamma + beta;
      float mx = gn;
#pragma unroll
      for (int mk = 1; mk <= 8; mk <<= 1) mx = fmaxf(mx, __shfl_xor(mx, mk));
      float ev = __expf(gn - mx);
      float ssum = ev;
#pragma unroll
      for (int mk = 1; mk <= 8; mk <<= 1) ssum += __shfl_xor(ssum, mk);
      gate[(size_t)(n0 + row) * NE + lr] = ev / ssum;
    }
  }

  for (int e = 0; e < NE; ++e) {
    // --- GEMM1: [64 x 128] K=512, wave owns 32 cols ---
    int cb = wid * 32;
    f32x4 a1[4][2];
#pragma unroll
    for (int m = 0; m < 4; ++m)
#pragma unroll
      for (int n = 0; n < 2; ++n) a1[m][n] = (f32x4){0.f, 0.f, 0.f, 0.f};
    const unsigned short* W1e = &W1t[e * NH1 * DDIM];
    for (int ks = 0; ks < 16; ++ks) {
      int k = ks * 32 + lg * 8;
      short8 av[4];
#pragma unroll
      for (int m = 0; m < 4; ++m) {
        int ar = m * 16 + lr;
        av[m] = *(short8*)&xl[(ar * DDIM + k) ^ ((ar & 7) << 3)];
      }
#pragma unroll
      for (int n = 0; n < 2; ++n) {
        short8 bv = *(const short8*)&W1e[(cb + n * 16 + lr) * DDIM + k];
#pragma unroll
        for (int m = 0; m < 4; ++m)
          a1[m][n] = __builtin_amdgcn_mfma_f32_16x16x32_bf16(av[m], bv, a1[m][n], 0, 0, 0);
      }
    }
    // --- BN1 + leaky relu -> h1 LDS (swizzled) ---
#pragma unroll
    for (int n = 0; n < 2; ++n) {
      int col = cb + n * 16 + lr;
      float mu = mean1[e * NH1 + col];
      float is = istd1[e * NH1 + col];
#pragma unroll
      for (int m = 0; m < 4; ++m)
#pragma unroll
        for (int r = 0; r < 4; ++r) {
          int row = m * 16 + lg * 4 + r;
          float v = (a1[m][n][r] - mu) * is;
          v = v >= 0.f ? v : 0.01f * v;
          h1l[(row * NH1 + col) ^ ((row & 7) << 3)] = f2bf(v);
        }
    }
    __syncthreads();
    // --- GEMM2: [64 x 64] K=128, wave owns 16 cols ---
    int cb2 = wid * 16;
    f32x4 a2[4];
#pragma unroll
    for (int m = 0; m < 4; ++m) a2[m] = (f32x4){0.f, 0.f, 0.f, 0.f};
    const unsigned short* W2e = &W2t[e * NH2 * NH1];
#pragma unroll
    for (int ks = 0; ks < 4; ++ks) {
      int k = ks * 32 + lg * 8;
      short8 bv = *(const short8*)&W2e[(cb2 + lr) * NH1 + k];
#pragma unroll
      for (int m = 0; m < 4; ++m) {
        int ar = m * 16 + lr;
        short8 av = *(short8*)&h1l[(ar * NH1 + k) ^ ((ar & 7) << 3)];
        a2[m] = __builtin_amdgcn_mfma_f32_16x16x32_bf16(av, bv, a2[m], 0, 0, 0);
      }
    }
    __syncthreads();   // all waves done reading h1l
    // --- h2_pre -> LDS (reuse h1l, plain layout) then coalesced global store ---
#pragma unroll
    for (int m = 0; m < 4; ++m)
#pragma unroll
      for (int r = 0; r < 4; ++r) {
        int row = m * 16 + lg * 4 + r;
        h1l[row * 64 + cb2 + lr] = f2bf(a2[m][r]);
      }
    __syncthreads();
    {
      int row = t >> 2, seg = t & 3;
      short8 v0 = *(short8*)&h1l[row * 64 + seg * 16];
      short8 v1 = *(short8*)&h1l[row * 64 + seg * 16 + 8];
      unsigned short* dst = &h2p[(size_t)(n0 + row) * 1024 + e * 64 + seg * 16];
      *(short8*)&dst[0] = v0;
      *(short8*)&dst[8] = v1;
    }
    __syncthreads();
  }
}

// ============ k_bn2stats: sum / sumsq over batch per (e, h2) ============
__global__ __launch_bounds__(1024) void k_bn2stats(const unsigned short* __restrict__ h2p,
                                                   float* __restrict__ s,
                                                   float* __restrict__ ss)
{
  int c = threadIdx.x;             // 0..1023 = (e*64+h)
  int n0 = blockIdx.x * 256;       // 256 blocks
  float a = 0.f, b = 0.f;
  for (int i = 0; i < 256; ++i) {
    float v = bf2f(h2p[(size_t)(n0 + i) * 1024 + c]);
    a += v; b += v * v;
  }
  atomicAdd(&s[c], a);
  atomicAdd(&ss[c], b);
}

// ============ k_tail: BN2+lrelu, score = h2n.v + bs, out = sum gate*score ============
__global__ __launch_bounds__(256) void k_tail(const unsigned short* __restrict__ h2p,
                                              const float* __restrict__ s,
                                              const float* __restrict__ ss,
                                              const float* __restrict__ vf,
                                              const float* __restrict__ gate,
                                              const float* __restrict__ bsp,
                                              float* __restrict__ out)
{
  int t = threadIdx.x;
  int l = t & 63, wid = t >> 6;
  int c0 = l * 16;
  float lm[16], li[16], lv[16];
#pragma unroll
  for (int j = 0; j < 16; ++j) {
    int c = c0 + j;
    float m = s[c] * (1.f / 65536.f);
    float var = ss[c] * (1.f / 65536.f) - m * m;
    lm[j] = m;
    li[j] = rsqrtf(var + 1e-4f);
    lv[j] = vf[c];
  }
  float bsv = bsp[0];
  for (int it = 0; it < 32; ++it) {
    int n = blockIdx.x * 128 + wid * 32 + it;
    const unsigned short* row = &h2p[(size_t)n * 1024 + c0];
    short8 v0 = *(const short8*)&row[0];
    short8 v1 = *(const short8*)&row[8];
    float p = 0.f;
#pragma unroll
    for (int j = 0; j < 8; ++j) {
      float h = bf2f((unsigned short)v0[j]);
      float hn = (h - lm[j]) * li[j];
      hn = hn >= 0.f ? hn : 0.01f * hn;
      p += hn * lv[j];
    }
#pragma unroll
    for (int j = 0; j < 8; ++j) {
      float h = bf2f((unsigned short)v1[j]);
      float hn = (h - lm[8 + j]) * li[8 + j];
      hn = hn >= 0.f ? hn : 0.01f * hn;
      p += hn * lv[8 + j];
    }
    p += __shfl_xor(p, 1);
    p += __shfl_xor(p, 2);
    float score = p + bsv;
    float gv = gate[(size_t)n * NE + (l >> 2)];
    float pr = gv * score;
    pr += __shfl_xor(pr, 4);
    pr += __shfl_xor(pr, 8);
    pr += __shfl_xor(pr, 16);
    pr += __shfl_xor(pr, 32);
    if (l == 0) out[n] = pr;
  }
}

extern "C" void kernel_launch(void* const* d_in, const int* in_sizes, int n_in,
                              void* d_out, int out_size, void* d_ws, size_t ws_size,
                              hipStream_t stream)
{
  (void)in_sizes; (void)n_in; (void)out_size; (void)ws_size;
  const float* x   = (const float*)d_in[0];
  const float* Wg  = (const float*)d_in[1];
  const float* bg  = (const float*)d_in[2];
  const float* lng = (const float*)d_in[3];
  const float* lnb = (const float*)d_in[4];
  const float* W1  = (const float*)d_in[5];
  const float* W2  = (const float*)d_in[6];
  const float* W3  = (const float*)d_in[7];
  const float* Ws  = (const float*)d_in[8];
  const float* bs  = (const float*)d_in[9];
  float* out = (float*)d_out;

  char* ws = (char*)d_ws;
  unsigned short* xT  = (unsigned short*)(ws + OFF_XT);
  unsigned short* h2p = (unsigned short*)(ws + OFF_H2);
  float* covp  = (float*)(ws + OFF_COVP);
  float* C     = (float*)(ws + OFF_C);
  float* gate  = (float*)(ws + OFF_GATE);
  unsigned short* W1t = (unsigned short*)(ws + OFF_W1T);
  unsigned short* W2t = (unsigned short*)(ws + OFF_W2T);
  unsigned short* Wgt = (unsigned short*)(ws + OFF_WGT);
  float* vf    = (float*)(ws + OFF_V);
  float* xbar  = (float*)(ws + OFF_XBAR);
  float* bn2s  = (float*)(ws + OFF_BN2S);
  float* bn2ss = (float*)(ws + OFF_BN2SS);
  float* mean1 = (float*)(ws + OFF_MEAN1);
  float* istd1 = (float*)(ws + OFF_ISTD1);

  hipLaunchKernelGGL(k_wprep, dim3(594), dim3(256), 0, stream,
                     W1, W2, W3, Wg, Ws, W1t, W2t, Wgt, vf, xbar);
  hipLaunchKernelGGL(k_prep, dim3(8192), dim3(256), 0, stream, x, xT, xbar);
  hipLaunchKernelGGL(k_cov, dim3(512), dim3(512), 0, stream, xT, covp);
  hipLaunchKernelGGL(k_covred, dim3(1024), dim3(256), 0, stream, covp, C);
  hipLaunchKernelGGL(k_bn1, dim3(256), dim3(256), 0, stream, C, xbar, W1t, mean1, istd1);
  hipLaunchKernelGGL(k_main, dim3(1024), dim3(256), 0, stream,
                     x, Wgt, W1t, W2t, bg, lng, lnb, mean1, istd1, gate, h2p);
  hipLaunchKernelGGL(k_bn2stats, dim3(256), dim3(1024), 0, stream, h2p, bn2s, bn2ss);
  hipLaunchKernelGGL(k_tail, dim3(512), dim3(256), 0, stream, h2p, bn2s, bn2ss, vf, gate, bs, out);
}